// Round 2
// baseline (1124.617 us; speedup 1.0000x reference)
//
#include <hip/hip_runtime.h>
#include <math.h>

#define Bsz 2
#define Ssz 2048
#define HIDs 3072
#define NHs 16
#define NKVs 8
#define HDs 256

typedef _Float16 f16;
typedef _Float16 f16x8 __attribute__((ext_vector_type(8)));
typedef _Float16 f16x4 __attribute__((ext_vector_type(4)));
typedef float f32x4 __attribute__((ext_vector_type(4)));

__device__ __forceinline__ void async16(const f16* g, f16* l) {
    __builtin_amdgcn_global_load_lds(
        (const __attribute__((address_space(1))) void*)g,
        (__attribute__((address_space(3))) void*)l, 16, 0, 0);
}

// 16-lane (quad-row) reductions on the VALU pipe via DPP row_ror.
__device__ __forceinline__ float row_max16(float v) {
    int t;
    t = __builtin_amdgcn_mov_dpp(__float_as_int(v), 0x121, 0xf, 0xf, false);
    v = fmaxf(v, __int_as_float(t));
    t = __builtin_amdgcn_mov_dpp(__float_as_int(v), 0x122, 0xf, 0xf, false);
    v = fmaxf(v, __int_as_float(t));
    t = __builtin_amdgcn_mov_dpp(__float_as_int(v), 0x124, 0xf, 0xf, false);
    v = fmaxf(v, __int_as_float(t));
    t = __builtin_amdgcn_mov_dpp(__float_as_int(v), 0x128, 0xf, 0xf, false);
    v = fmaxf(v, __int_as_float(t));
    return v;
}
__device__ __forceinline__ float row_sum16(float v) {
    int t;
    t = __builtin_amdgcn_mov_dpp(__float_as_int(v), 0x121, 0xf, 0xf, false);
    v = v + __int_as_float(t);
    t = __builtin_amdgcn_mov_dpp(__float_as_int(v), 0x122, 0xf, 0xf, false);
    v = v + __int_as_float(t);
    t = __builtin_amdgcn_mov_dpp(__float_as_int(v), 0x124, 0xf, 0xf, false);
    v = v + __int_as_float(t);
    t = __builtin_amdgcn_mov_dpp(__float_as_int(v), 0x128, 0xf, 0xf, false);
    v = v + __int_as_float(t);
    return v;
}

// ---------------- fused cast fp32 -> fp16 for all 5 inputs (1 launch) ----------------
#define N4_HS  3145728
#define N4_WQ  3145728
#define N4_WK  1572864
#define N4_WV  1572864
#define N4_WO  3145728
#define N4_TOT (N4_HS + N4_WQ + N4_WK + N4_WV + N4_WO)

__global__ void cast_all_kernel(const float4* __restrict__ hs, const float4* __restrict__ wq,
                                const float4* __restrict__ wk, const float4* __restrict__ wv,
                                const float4* __restrict__ wo,
                                f16x4* __restrict__ hs_h, f16x4* __restrict__ wq_h,
                                f16x4* __restrict__ wk_h, f16x4* __restrict__ wv_h,
                                f16x4* __restrict__ wo_h) {
    int i = blockIdx.x * blockDim.x + threadIdx.x;
    const float4* src; f16x4* dst; int off;
    if (i < N4_HS)                       { src = hs; dst = hs_h; off = i; }
    else if (i < N4_HS + N4_WQ)          { src = wq; dst = wq_h; off = i - N4_HS; }
    else if (i < N4_HS + N4_WQ + N4_WK)  { src = wk; dst = wk_h; off = i - (N4_HS + N4_WQ); }
    else if (i < N4_TOT - N4_WO)         { src = wv; dst = wv_h; off = i - (N4_HS + N4_WQ + N4_WK); }
    else                                 { src = wo; dst = wo_h; off = i - (N4_TOT - N4_WO); }
    float4 v = src[off];
    f16x4 r;
    r[0] = (f16)v.x; r[1] = (f16)v.y; r[2] = (f16)v.z; r[3] = (f16)v.w;
    dst[off] = r;
}

// ---- NT GEMM (m97 structure): C[M,N] = A[M,K]*B[N,K]^T, f16 in, f32 out ----
__global__ __launch_bounds__(256) void gemm_nt_f16(
    const f16* __restrict__ A, const f16* __restrict__ Bm, float* __restrict__ C,
    int M, int N, int K)
{
    __shared__ __align__(16) f16 As[128 * 32];
    __shared__ __align__(16) f16 Bs[128 * 32];
    const int tid  = threadIdx.x;
    const int wave = tid >> 6, lane = tid & 63;
    const int l15  = lane & 15, quad = lane >> 4;
    const int m0 = blockIdx.y * 128, n0 = blockIdx.x * 128;
    const int wm = (wave >> 1) * 64, wn = (wave & 1) * 64;
    const int srow = wave * 32 + (lane >> 2);
    const int scol = (lane & 3) * 8;

    f32x4 acc[4][4];
    const f32x4 fz = {0.f, 0.f, 0.f, 0.f};
#pragma unroll
    for (int i = 0; i < 4; i++)
#pragma unroll
        for (int j = 0; j < 4; j++) acc[i][j] = fz;

    const f16* Ag0 = A  + (size_t)(m0 + srow) * K + scol;
    const f16* Ag1 = A  + (size_t)(m0 + srow + 16) * K + scol;
    const f16* Bg0 = Bm + (size_t)(n0 + srow) * K + scol;
    const f16* Bg1 = Bm + (size_t)(n0 + srow + 16) * K + scol;
    f16* Al0 = As + (wave * 32) * 32;
    f16* Al1 = As + (wave * 32 + 16) * 32;
    f16* Bl0 = Bs + (wave * 32) * 32;
    f16* Bl1 = Bs + (wave * 32 + 16) * 32;

    for (int k0 = 0; k0 < K; k0 += 32) {
        __syncthreads();
        async16(Ag0 + k0, Al0);
        async16(Ag1 + k0, Al1);
        async16(Bg0 + k0, Bl0);
        async16(Bg1 + k0, Bl1);
        __syncthreads();
        f16x8 af[4], bfr[4];
#pragma unroll
        for (int i = 0; i < 4; i++)
            af[i] = *(const f16x8*)(As + (wm + i * 16 + l15) * 32 + quad * 8);
#pragma unroll
        for (int j = 0; j < 4; j++)
            bfr[j] = *(const f16x8*)(Bs + (wn + j * 16 + l15) * 32 + quad * 8);
#pragma unroll
        for (int i = 0; i < 4; i++)
#pragma unroll
            for (int j = 0; j < 4; j++)
                acc[i][j] = __builtin_amdgcn_mfma_f32_16x16x32_f16(af[i], bfr[j], acc[i][j], 0, 0, 0);
    }
#pragma unroll
    for (int i = 0; i < 4; i++) {
        const int r = m0 + wm + i * 16 + quad * 4;
#pragma unroll
        for (int j = 0; j < 4; j++) {
            const int c = n0 + wn + j * 16 + l15;
#pragma unroll
            for (int rr = 0; rr < 4; rr++)
                C[(size_t)(r + rr) * N + c] = acc[i][j][rr];
        }
    }
}

// ---------------- RoPE for Q (scale 1/sqrt(HD) folded in) ----------------
__global__ void rope_q_kernel(const float* __restrict__ qp, const float* __restrict__ cosb,
                              const float* __restrict__ sinb, f16* __restrict__ qo) {
    const int s = blockIdx.x, h = blockIdx.y, b = blockIdx.z;
    const int d = threadIdx.x;
    const float* row = qp + (size_t)(b * Ssz + s) * (NHs * HDs) + h * HDs;
    float x = row[d];
    float other = (d < 128) ? -row[d + 128] : row[d - 128];
    float val = (x * cosb[s * HDs + d] + other * sinb[s * HDs + d]) * 0.0625f;
    qo[((size_t)(b * NHs + h) * Ssz + s) * HDs + d] = (f16)val;
}

// ---------------- RoPE + BFP4 quantize for K ----------------
__global__ void rope_quant_k_kernel(const float* __restrict__ kp, const float* __restrict__ cosb,
                                    const float* __restrict__ sinb, f16* __restrict__ ko) {
    const int s = blockIdx.x, h = blockIdx.y, b = blockIdx.z;
    const int d = threadIdx.x;
    const float* row = kp + (size_t)(b * Ssz + s) * (NKVs * HDs) + h * HDs;
    float x = row[d];
    float other = (d < 128) ? -row[d + 128] : row[d - 128];
    float val = x * cosb[s * HDs + d] + other * sinb[s * HDs + d];
    __shared__ float red[256];
    red[d] = fabsf(val);
    __syncthreads();
    for (int off = 64; off >= 1; off >>= 1) {
        if ((d & 127) < off) red[d] = fmaxf(red[d], red[d + off]);
        __syncthreads();
    }
    float maxabs = red[d & 128];
    float out;
    if (maxabs > 0.f) {
        int ex;
        frexpf(maxabs, &ex);                 // floor(log2(maxabs)) = ex-1 exactly
        float scale = ldexpf(1.0f, ex - 3);  // 2^(e - (bits-2)), bits=4
        float q = rintf(val / scale);
        q = fminf(7.f, fmaxf(-7.f, q));
        out = q * scale;
    } else out = 0.f;
    ko[((size_t)(b * NKVs + h) * Ssz + s) * HDs + d] = (f16)out;
}

// -------- V: fp32 proj [b][s][kh*256+d] -> f16 Vt [b][kh][d][s] (transposed) --------
__global__ __launch_bounds__(256) void transpose_v_kernel(
    const float* __restrict__ proj, f16* __restrict__ vt)
{
    const int s0 = blockIdx.x * 64, c0 = blockIdx.y * 64, b = blockIdx.z;
    const int tid = threadIdx.x;
    __shared__ f16 T[64 * 72];
    {
        const int r = tid >> 2, cc = (tid & 3) * 16;
        const float* src = proj + (size_t)(b * Ssz + s0 + r) * (NKVs * HDs) + c0 + cc;
        f16 tmp[16];
#pragma unroll
        for (int q4 = 0; q4 < 4; q4++) {
            float4 v = *(const float4*)(src + q4 * 4);
            tmp[q4 * 4 + 0] = (f16)v.x; tmp[q4 * 4 + 1] = (f16)v.y;
            tmp[q4 * 4 + 2] = (f16)v.z; tmp[q4 * 4 + 3] = (f16)v.w;
        }
        *(f16x8*)(T + r * 72 + cc)     = *(f16x8*)(tmp);
        *(f16x8*)(T + r * 72 + cc + 8) = *(f16x8*)(tmp + 8);
    }
    __syncthreads();
    {
        const int d = tid >> 2, sc = (tid & 3) * 16;
        f16 tmp[16];
#pragma unroll
        for (int j = 0; j < 16; j++) tmp[j] = T[(sc + j) * 72 + d];
        const int col = c0 + d;
        const int kh = col >> 8, dd = col & 255;
        f16* dst = vt + ((size_t)(b * NKVs + kh) * HDs + dd) * Ssz + s0 + sc;
        *(f16x8*)(dst)     = *(f16x8*)(tmp);
        *(f16x8*)(dst + 8) = *(f16x8*)(tmp + 8);
    }
}

// ---- flash attention v7: double-buffered K/V with STATICALLY-distinct LDS
// arrays (Ks0/Ks1, Vs0/Vs1) + 2x-unrolled KV loop, so alias analysis can
// prove ds_reads (compute, buf A) never touch in-flight global_load_lds
// destinations (prefetch, buf B) -> no compiler-inserted vmcnt(0) before the
// compute phase. One __syncthreads per tile (its vmcnt(0) drain lands AFTER
// the full compute phase, hiding load latency). Swizzles + defer-max kept
// from v6. LDS 74 KB -> 2 blocks/CU (grid = 2/CU anyway).
__global__ __launch_bounds__(256, 2) void attn_kernel(
    const f16* __restrict__ Q,   // [B][NH][S][HD], pre-scaled by 1/16
    const f16* __restrict__ Kq,  // [B][NKV][S][HD] quantized
    const f16* __restrict__ Vt,  // [B][NKV][HD][S] transposed
    f16* __restrict__ O)         // [B][S][NH*HD]
{
    const int qt = (gridDim.x - 1) - blockIdx.x;   // longest blocks first
    const int h = blockIdx.y, b = blockIdx.z;
    const int kh = h >> 1;
    const int tid = threadIdx.x;
    const int wave = tid >> 6, lane = tid & 63;
    const int l15 = lane & 15, quad = lane >> 4;
    const int wrow = qt * 128 + wave * 32;         // wave's first Q row (32 rows)

    const f16* Qb  = Q  + ((size_t)(b * NHs  + h)  * Ssz) * HDs;
    const f16* Kg  = Kq + ((size_t)(b * NKVs + kh) * Ssz) * HDs;
    const f16* Vtg = Vt + ((size_t)(b * NKVs + kh) * HDs) * Ssz;

    __shared__ __align__(16) f16 Ks0[32 * 256];  // [kv][d], chunks ^ (row&7)
    __shared__ __align__(16) f16 Ks1[32 * 256];
    __shared__ __align__(16) f16 Vs0[256 * 32];  // [d][kv], chunks ^ ((row>>1)&3)
    __shared__ __align__(16) f16 Vs1[256 * 32];
    __shared__ __align__(16) f16 Pl[4 * 32 * 40];
    f16* Pw = Pl + wave * 32 * 40;

    const int k_r  = lane >> 5;          // row within staged pair
    const int k_c  = lane & 31;          // 16B chunk within 512B row
    const int v_r  = lane >> 2;          // d-row within 16-group
    const int v_gc = (lane & 3) ^ ((v_r >> 1) & 3);  // pre-swizzled global kv-chunk

    // stage K/V tile kt2 into the given LDS buffers (linear dest, swizzle via global src)
    auto stage = [&](int kt2, f16* Ksd, f16* Vsd) {
        const int kvb_ = kt2 * 32;
#pragma unroll
        for (int t = 0; t < 4; t++) {
            const int r2 = wave * 8 + t * 2;
            const int gc = k_c ^ ((2 * t + k_r) & 7);   // (row&7) since wave*8 ≡ 0 (mod 8)
            async16(Kg + (size_t)(kvb_ + r2 + k_r) * 256 + gc * 8, Ksd + r2 * 256);
        }
#pragma unroll
        for (int t = 0; t < 4; t++) {
            const int d0 = wave * 64 + t * 16;
            async16(Vtg + (size_t)(d0 + v_r) * Ssz + kvb_ + v_gc * 8, Vsd + d0 * 32);
        }
    };

    f16x8 qf0[8], qf1[8];
    {
        const f16* qrow0 = Qb + (size_t)(wrow + l15) * HDs + quad * 8;
        const f16* qrow1 = qrow0 + (size_t)16 * HDs;
#pragma unroll
        for (int ks = 0; ks < 8; ks++) {
            qf0[ks] = *(const f16x8*)(qrow0 + ks * 32);
            qf1[ks] = *(const f16x8*)(qrow1 + ks * 32);
        }
    }

    const f32x4 fz = {0.f, 0.f, 0.f, 0.f};
    f32x4 accO0[16], accO1[16];
#pragma unroll
    for (int jn = 0; jn < 16; jn++) { accO0[jn] = fz; accO1[jn] = fz; }
    float mrow0[4], mrow1[4], lp0[4], lp1[4];
#pragma unroll
    for (int r = 0; r < 4; r++) { mrow0[r] = -1e30f; mrow1[r] = -1e30f; lp0[r] = 0.f; lp1[r] = 0.f; }

    const int nk = 4 * qt + 4;           // always even
    const int wave_max_row = wrow + 31;
    const int kswz = l15 & 7;            // K read swizzle (rows l15 and 16+l15 share &7)
    const int vswz = (l15 >> 1) & 3;     // V read swizzle

    // full per-tile compute: QK^T -> online softmax (defer-max) -> PV
    auto compute = [&](int kvb, const f16* Ksc, const f16* Vsc) {
        f32x4 s00 = fz, s01 = fz, s10 = fz, s11 = fz;
#pragma unroll
        for (int ks = 0; ks < 8; ks++) {
            const int cpos = ((ks * 4 + quad) ^ kswz) * 8;
            f16x8 kf0 = *(const f16x8*)(Ksc + l15 * 256 + cpos);
            f16x8 kf1 = *(const f16x8*)(Ksc + (16 + l15) * 256 + cpos);
            s00 = __builtin_amdgcn_mfma_f32_16x16x32_f16(qf0[ks], kf0, s00, 0, 0, 0);
            s01 = __builtin_amdgcn_mfma_f32_16x16x32_f16(qf0[ks], kf1, s01, 0, 0, 0);
            s10 = __builtin_amdgcn_mfma_f32_16x16x32_f16(qf1[ks], kf0, s10, 0, 0, 0);
            s11 = __builtin_amdgcn_mfma_f32_16x16x32_f16(qf1[ks], kf1, s11, 0, 0, 0);
        }
        float a0[4], a1[4];
        bool need = false;
        const bool diag = (kvb + 31 > wrow);   // any masking in this tile
#pragma unroll
        for (int r = 0; r < 4; r++) {
            // subtile 0: rows wrow + quad*4 + r
            float x0 = s00[r], x1 = s01[r];
            const int row0 = wrow + quad * 4 + r;
            if (diag) {
                if (kvb + l15 > row0)      x0 = -1e30f;
                if (kvb + 16 + l15 > row0) x1 = -1e30f;
            }
            float rmax = row_max16(fmaxf(x0, x1));
            float mold = mrow0[r];
            bool upd = rmax > mold + 8.f;      // defer-max, THR=8
            float mnew = upd ? rmax : mold;
            a0[r] = upd ? __expf(mold - rmax) : 1.0f;
            need = need || upd;
            float p0 = __expf(x0 - mnew);
            float p1 = __expf(x1 - mnew);
            lp0[r] = lp0[r] * a0[r] + (p0 + p1);
            mrow0[r] = mnew;
            Pw[(quad * 4 + r) * 40 + l15]      = (f16)p0;
            Pw[(quad * 4 + r) * 40 + 16 + l15] = (f16)p1;
            // subtile 1: rows wrow + 16 + quad*4 + r
            float y0 = s10[r], y1 = s11[r];
            const int row1 = row0 + 16;
            if (diag) {
                if (kvb + l15 > row1)      y0 = -1e30f;
                if (kvb + 16 + l15 > row1) y1 = -1e30f;
            }
            float rmax1 = row_max16(fmaxf(y0, y1));
            float mold1 = mrow1[r];
            bool upd1 = rmax1 > mold1 + 8.f;
            float mnew1 = upd1 ? rmax1 : mold1;
            a1[r] = upd1 ? __expf(mold1 - rmax1) : 1.0f;
            need = need || upd1;
            float q0 = __expf(y0 - mnew1);
            float q1 = __expf(y1 - mnew1);
            lp1[r] = lp1[r] * a1[r] + (q0 + q1);
            mrow1[r] = mnew1;
            Pw[(16 + quad * 4 + r) * 40 + l15]      = (f16)q0;
            Pw[(16 + quad * 4 + r) * 40 + 16 + l15] = (f16)q1;
        }
        if (__any(need)) {
#pragma unroll
            for (int jn = 0; jn < 16; jn++) {
                f32x4 t0 = accO0[jn], t1 = accO1[jn];
                t0[0] *= a0[0]; t0[1] *= a0[1]; t0[2] *= a0[2]; t0[3] *= a0[3];
                t1[0] *= a1[0]; t1[1] *= a1[1]; t1[2] *= a1[2]; t1[3] *= a1[3];
                accO0[jn] = t0; accO1[jn] = t1;
            }
        }
        // P (C-layout) -> A-layout via same-wave LDS round trip
        f16x8 pf0 = *(const f16x8*)(Pw + l15 * 40 + quad * 8);
        f16x8 pf1 = *(const f16x8*)(Pw + (16 + l15) * 40 + quad * 8);
#pragma unroll
        for (int jn = 0; jn < 16; jn++) {
            f16x8 vf = *(const f16x8*)(Vsc + (jn * 16 + l15) * 32 + (quad ^ vswz) * 8);
            accO0[jn] = __builtin_amdgcn_mfma_f32_16x16x32_f16(pf0, vf, accO0[jn], 0, 0, 0);
            accO1[jn] = __builtin_amdgcn_mfma_f32_16x16x32_f16(pf1, vf, accO1[jn], 0, 0, 0);
        }
    };

    stage(0, Ks0, Vs0);
    __syncthreads();                     // tile 0 visible

    for (int kt = 0; kt < nk; kt += 2) {
        // tile kt lives in buf0; prefetch kt+1 into buf1, then compute buf0
        stage(kt + 1, Ks1, Vs1);
        const int kvb0 = kt * 32;
        if (kvb0 <= wave_max_row) compute(kvb0, Ks0, Vs0);
        __syncthreads();                 // drains prefetch; buf0 free to overwrite
        // tile kt+1 lives in buf1; prefetch kt+2 into buf0, then compute buf1
        if (kt + 2 < nk) stage(kt + 2, Ks0, Vs0);
        const int kvb1 = kvb0 + 32;
        if (kvb1 <= wave_max_row) compute(kvb1, Ks1, Vs1);
        __syncthreads();                 // drains prefetch; buf1 free to overwrite
    }

#pragma unroll
    for (int r = 0; r < 4; r++) {
        const int row0 = wrow + quad * 4 + r;
        const float inv0 = 1.0f / row_sum16(lp0[r]);
        f16* orow0 = O + ((size_t)(b * Ssz) + row0) * (NHs * HDs) + h * HDs;
#pragma unroll
        for (int jn = 0; jn < 16; jn++)
            orow0[jn * 16 + l15] = (f16)(accO0[jn][r] * inv0);
        const int row1 = row0 + 16;
        const float inv1 = 1.0f / row_sum16(lp1[r]);
        f16* orow1 = O + ((size_t)(b * Ssz) + row1) * (NHs * HDs) + h * HDs;
#pragma unroll
        for (int jn = 0; jn < 16; jn++)
            orow1[jn * 16 + l15] = (f16)(accO1[jn][r] * inv1);
    }
}

// ---------------- launcher ----------------
extern "C" void kernel_launch(void* const* d_in, const int* in_sizes, int n_in,
                              void* d_out, int out_size, void* d_ws, size_t ws_size,
                              hipStream_t stream) {
    const float* hs   = (const float*)d_in[0];
    const float* Wq   = (const float*)d_in[1];
    const float* Wk   = (const float*)d_in[2];
    const float* Wv   = (const float*)d_in[3];
    const float* Wo   = (const float*)d_in[4];
    const float* cosb = (const float*)d_in[5];
    const float* sinb = (const float*)d_in[6];
    float* out = (float*)d_out;

    char* ws = (char*)d_ws;
    f16*   hs_h = (f16*)(ws);                    // 25165824 B  (hidden f16)
    f16*   wo_h = (f16*)(ws + 25165824);         // 25165824 B  (Wo f16)
    float* proj = (float*)(ws + 50331648);       // 67108864 B  (reused)
    f16*   q_h  = (f16*)(ws + 117440512);        // 33554432 B  (Wq f16 first, then roped Q)
    f16*   k_h  = (f16*)(ws + 150994944);        // 16777216 B  (Wk f16 first, then quant K)
    f16*   vt_h = (f16*)(ws + 167772160);        // 16777216 B  (Wv f16 first, then Vt)
    f16*   ao_h = (f16*)proj;                    // attn output reuses proj region

    // one fused cast: hs->hs_h, Wq->q_h, Wk->k_h, Wv->vt_h, Wo->wo_h
    cast_all_kernel<<<N4_TOT / 256, 256, 0, stream>>>(
        (const float4*)hs, (const float4*)Wq, (const float4*)Wk,
        (const float4*)Wv, (const float4*)Wo,
        (f16x4*)hs_h, (f16x4*)q_h, (f16x4*)k_h, (f16x4*)vt_h, (f16x4*)wo_h);

    // Q projection (B = Wq living in q_h region; rope then overwrites q_h)
    gemm_nt_f16<<<dim3(4096 / 128, 4096 / 128), 256, 0, stream>>>(hs_h, q_h, proj, 4096, 4096, 3072);
    rope_q_kernel<<<dim3(Ssz, NHs, Bsz), 256, 0, stream>>>(proj, cosb, sinb, q_h);
    // K projection + quantize (B = Wk in k_h; then overwritten)
    gemm_nt_f16<<<dim3(2048 / 128, 4096 / 128), 256, 0, stream>>>(hs_h, k_h, proj, 4096, 2048, 3072);
    rope_quant_k_kernel<<<dim3(Ssz, NKVs, Bsz), 256, 0, stream>>>(proj, cosb, sinb, k_h);
    // V projection + transpose (B = Wv in vt_h; then overwritten)
    gemm_nt_f16<<<dim3(2048 / 128, 4096 / 128), 256, 0, stream>>>(hs_h, vt_h, proj, 4096, 2048, 3072);
    transpose_v_kernel<<<dim3(Ssz / 64, (NKVs * HDs) / 64, Bsz), 256, 0, stream>>>(proj, vt_h);
    // attention: Q-tile 128 -> 512 blocks, longest-first
    attn_kernel<<<dim3(Ssz / 128, NHs, Bsz), 256, 0, stream>>>(q_h, k_h, vt_h, ao_h);
    // output projection -> d_out
    gemm_nt_f16<<<dim3(3072 / 128, 4096 / 128), 256, 0, stream>>>(ao_h, wo_h, out, 4096, 3072, 4096);
}

// Round 3
// 970.709 us; speedup vs baseline: 1.1586x; 1.1586x over previous
//
#include <hip/hip_runtime.h>
#include <math.h>

#define Bsz 2
#define Ssz 2048
#define HIDs 3072
#define NHs 16
#define NKVs 8
#define HDs 256

typedef _Float16 f16;
typedef _Float16 f16x8 __attribute__((ext_vector_type(8)));
typedef _Float16 f16x4 __attribute__((ext_vector_type(4)));
typedef float f32x4 __attribute__((ext_vector_type(4)));

__device__ __forceinline__ void async16(const f16* g, f16* l) {
    __builtin_amdgcn_global_load_lds(
        (const __attribute__((address_space(1))) void*)g,
        (__attribute__((address_space(3))) void*)l, 16, 0, 0);
}

// 16-lane (quad-row) reductions on the VALU pipe via DPP row_ror.
__device__ __forceinline__ float row_max16(float v) {
    int t;
    t = __builtin_amdgcn_mov_dpp(__float_as_int(v), 0x121, 0xf, 0xf, false);
    v = fmaxf(v, __int_as_float(t));
    t = __builtin_amdgcn_mov_dpp(__float_as_int(v), 0x122, 0xf, 0xf, false);
    v = fmaxf(v, __int_as_float(t));
    t = __builtin_amdgcn_mov_dpp(__float_as_int(v), 0x124, 0xf, 0xf, false);
    v = fmaxf(v, __int_as_float(t));
    t = __builtin_amdgcn_mov_dpp(__float_as_int(v), 0x128, 0xf, 0xf, false);
    v = fmaxf(v, __int_as_float(t));
    return v;
}
__device__ __forceinline__ float row_sum16(float v) {
    int t;
    t = __builtin_amdgcn_mov_dpp(__float_as_int(v), 0x121, 0xf, 0xf, false);
    v = v + __int_as_float(t);
    t = __builtin_amdgcn_mov_dpp(__float_as_int(v), 0x122, 0xf, 0xf, false);
    v = v + __int_as_float(t);
    t = __builtin_amdgcn_mov_dpp(__float_as_int(v), 0x124, 0xf, 0xf, false);
    v = v + __int_as_float(t);
    t = __builtin_amdgcn_mov_dpp(__float_as_int(v), 0x128, 0xf, 0xf, false);
    v = v + __int_as_float(t);
    return v;
}

// ---------------- fused cast fp32 -> fp16 for all 5 inputs (1 launch) ----------------
#define N4_HS  3145728
#define N4_WQ  3145728
#define N4_WK  1572864
#define N4_WV  1572864
#define N4_WO  3145728
#define N4_TOT (N4_HS + N4_WQ + N4_WK + N4_WV + N4_WO)

__global__ void cast_all_kernel(const float4* __restrict__ hs, const float4* __restrict__ wq,
                                const float4* __restrict__ wk, const float4* __restrict__ wv,
                                const float4* __restrict__ wo,
                                f16x4* __restrict__ hs_h, f16x4* __restrict__ wq_h,
                                f16x4* __restrict__ wk_h, f16x4* __restrict__ wv_h,
                                f16x4* __restrict__ wo_h) {
    int i = blockIdx.x * blockDim.x + threadIdx.x;
    const float4* src; f16x4* dst; int off;
    if (i < N4_HS)                       { src = hs; dst = hs_h; off = i; }
    else if (i < N4_HS + N4_WQ)          { src = wq; dst = wq_h; off = i - N4_HS; }
    else if (i < N4_HS + N4_WQ + N4_WK)  { src = wk; dst = wk_h; off = i - (N4_HS + N4_WQ); }
    else if (i < N4_TOT - N4_WO)         { src = wv; dst = wv_h; off = i - (N4_HS + N4_WQ + N4_WK); }
    else                                 { src = wo; dst = wo_h; off = i - (N4_TOT - N4_WO); }
    float4 v = src[off];
    f16x4 r;
    r[0] = (f16)v.x; r[1] = (f16)v.y; r[2] = (f16)v.z; r[3] = (f16)v.w;
    dst[off] = r;
}

// ---- NT GEMM (m97 structure): C[M,N] = A[M,K]*B[N,K]^T, f16 in, f32 out ----
__global__ __launch_bounds__(256) void gemm_nt_f16(
    const f16* __restrict__ A, const f16* __restrict__ Bm, float* __restrict__ C,
    int M, int N, int K)
{
    __shared__ __align__(16) f16 As[128 * 32];
    __shared__ __align__(16) f16 Bs[128 * 32];
    const int tid  = threadIdx.x;
    const int wave = tid >> 6, lane = tid & 63;
    const int l15  = lane & 15, quad = lane >> 4;
    const int m0 = blockIdx.y * 128, n0 = blockIdx.x * 128;
    const int wm = (wave >> 1) * 64, wn = (wave & 1) * 64;
    const int srow = wave * 32 + (lane >> 2);
    const int scol = (lane & 3) * 8;

    f32x4 acc[4][4];
    const f32x4 fz = {0.f, 0.f, 0.f, 0.f};
#pragma unroll
    for (int i = 0; i < 4; i++)
#pragma unroll
        for (int j = 0; j < 4; j++) acc[i][j] = fz;

    const f16* Ag0 = A  + (size_t)(m0 + srow) * K + scol;
    const f16* Ag1 = A  + (size_t)(m0 + srow + 16) * K + scol;
    const f16* Bg0 = Bm + (size_t)(n0 + srow) * K + scol;
    const f16* Bg1 = Bm + (size_t)(n0 + srow + 16) * K + scol;
    f16* Al0 = As + (wave * 32) * 32;
    f16* Al1 = As + (wave * 32 + 16) * 32;
    f16* Bl0 = Bs + (wave * 32) * 32;
    f16* Bl1 = Bs + (wave * 32 + 16) * 32;

    for (int k0 = 0; k0 < K; k0 += 32) {
        __syncthreads();
        async16(Ag0 + k0, Al0);
        async16(Ag1 + k0, Al1);
        async16(Bg0 + k0, Bl0);
        async16(Bg1 + k0, Bl1);
        __syncthreads();
        f16x8 af[4], bfr[4];
#pragma unroll
        for (int i = 0; i < 4; i++)
            af[i] = *(const f16x8*)(As + (wm + i * 16 + l15) * 32 + quad * 8);
#pragma unroll
        for (int j = 0; j < 4; j++)
            bfr[j] = *(const f16x8*)(Bs + (wn + j * 16 + l15) * 32 + quad * 8);
#pragma unroll
        for (int i = 0; i < 4; i++)
#pragma unroll
            for (int j = 0; j < 4; j++)
                acc[i][j] = __builtin_amdgcn_mfma_f32_16x16x32_f16(af[i], bfr[j], acc[i][j], 0, 0, 0);
    }
#pragma unroll
    for (int i = 0; i < 4; i++) {
        const int r = m0 + wm + i * 16 + quad * 4;
#pragma unroll
        for (int j = 0; j < 4; j++) {
            const int c = n0 + wn + j * 16 + l15;
#pragma unroll
            for (int rr = 0; rr < 4; rr++)
                C[(size_t)(r + rr) * N + c] = acc[i][j][rr];
        }
    }
}

// ---------------- RoPE for Q (scale 1/sqrt(HD) folded in) ----------------
__global__ void rope_q_kernel(const float* __restrict__ qp, const float* __restrict__ cosb,
                              const float* __restrict__ sinb, f16* __restrict__ qo) {
    const int s = blockIdx.x, h = blockIdx.y, b = blockIdx.z;
    const int d = threadIdx.x;
    const float* row = qp + (size_t)(b * Ssz + s) * (NHs * HDs) + h * HDs;
    float x = row[d];
    float other = (d < 128) ? -row[d + 128] : row[d - 128];
    float val = (x * cosb[s * HDs + d] + other * sinb[s * HDs + d]) * 0.0625f;
    qo[((size_t)(b * NHs + h) * Ssz + s) * HDs + d] = (f16)val;
}

// ---------------- RoPE + BFP4 quantize for K ----------------
__global__ void rope_quant_k_kernel(const float* __restrict__ kp, const float* __restrict__ cosb,
                                    const float* __restrict__ sinb, f16* __restrict__ ko) {
    const int s = blockIdx.x, h = blockIdx.y, b = blockIdx.z;
    const int d = threadIdx.x;
    const float* row = kp + (size_t)(b * Ssz + s) * (NKVs * HDs) + h * HDs;
    float x = row[d];
    float other = (d < 128) ? -row[d + 128] : row[d - 128];
    float val = x * cosb[s * HDs + d] + other * sinb[s * HDs + d];
    __shared__ float red[256];
    red[d] = fabsf(val);
    __syncthreads();
    for (int off = 64; off >= 1; off >>= 1) {
        if ((d & 127) < off) red[d] = fmaxf(red[d], red[d + off]);
        __syncthreads();
    }
    float maxabs = red[d & 128];
    float out;
    if (maxabs > 0.f) {
        int ex;
        frexpf(maxabs, &ex);                 // floor(log2(maxabs)) = ex-1 exactly
        float scale = ldexpf(1.0f, ex - 3);  // 2^(e - (bits-2)), bits=4
        float q = rintf(val / scale);
        q = fminf(7.f, fmaxf(-7.f, q));
        out = q * scale;
    } else out = 0.f;
    ko[((size_t)(b * NKVs + h) * Ssz + s) * HDs + d] = (f16)out;
}

// -------- V: fp32 proj [b][s][kh*256+d] -> f16 Vt [b][kh][d][s] (transposed) --------
__global__ __launch_bounds__(256) void transpose_v_kernel(
    const float* __restrict__ proj, f16* __restrict__ vt)
{
    const int s0 = blockIdx.x * 64, c0 = blockIdx.y * 64, b = blockIdx.z;
    const int tid = threadIdx.x;
    __shared__ f16 T[64 * 72];
    {
        const int r = tid >> 2, cc = (tid & 3) * 16;
        const float* src = proj + (size_t)(b * Ssz + s0 + r) * (NKVs * HDs) + c0 + cc;
        f16 tmp[16];
#pragma unroll
        for (int q4 = 0; q4 < 4; q4++) {
            float4 v = *(const float4*)(src + q4 * 4);
            tmp[q4 * 4 + 0] = (f16)v.x; tmp[q4 * 4 + 1] = (f16)v.y;
            tmp[q4 * 4 + 2] = (f16)v.z; tmp[q4 * 4 + 3] = (f16)v.w;
        }
        *(f16x8*)(T + r * 72 + cc)     = *(f16x8*)(tmp);
        *(f16x8*)(T + r * 72 + cc + 8) = *(f16x8*)(tmp + 8);
    }
    __syncthreads();
    {
        const int d = tid >> 2, sc = (tid & 3) * 16;
        f16 tmp[16];
#pragma unroll
        for (int j = 0; j < 16; j++) tmp[j] = T[(sc + j) * 72 + d];
        const int col = c0 + d;
        const int kh = col >> 8, dd = col & 255;
        f16* dst = vt + ((size_t)(b * NKVs + kh) * HDs + dd) * Ssz + s0 + sc;
        *(f16x8*)(dst)     = *(f16x8*)(tmp);
        *(f16x8*)(dst + 8) = *(f16x8*)(tmp + 8);
    }
}

// ---- flash attention v8: R0 serial 2-barrier structure (known-best) +
// XCD-locality block remap. Grid (16,16,2): linear wgid round-robins XCDs
// (xcd = wgid%8), so we remap so each (b,kh) K/V working set (2 MB) lives
// entirely on ONE XCD (2 pairs/XCD = 4 MB = L2). qt paired as (15-q, q)
// across the two pairs so co-resident blocks sum to constant 68 tiles.
// v6 swizzles (K: chunk^(row&7), V: chunk^((row>>1)&3)) + defer-max kept.
__global__ __launch_bounds__(256, 2) void attn_kernel(
    const f16* __restrict__ Q,   // [B][NH][S][HD], pre-scaled by 1/16
    const f16* __restrict__ Kq,  // [B][NKV][S][HD] quantized
    const f16* __restrict__ Vt,  // [B][NKV][HD][S] transposed
    f16* __restrict__ O)         // [B][S][NH*HD]
{
    // ---- XCD-locality remap (bijective over 512 blocks) ----
    const int flat = blockIdx.x + (blockIdx.y << 4) + (blockIdx.z << 8);
    const int xcd  = flat & 7;
    const int slot = flat >> 3;          // 0..63
    const int psel = slot >> 5;          // 0|1: which of this XCD's 2 pairs
    const int pair = (xcd << 1) | psel;  // 0..15 == (b*8 + kh)
    const int b    = pair >> 3;
    const int kh   = pair & 7;
    const int sub  = slot & 31;          // 0..31 within pair
    const int h    = (kh << 1) | (sub >> 4);
    const int qt_raw = sub & 15;
    const int qt   = psel ? qt_raw : (15 - qt_raw);  // pair0 longest-first

    const int tid = threadIdx.x;
    const int wave = tid >> 6, lane = tid & 63;
    const int l15 = lane & 15, quad = lane >> 4;
    const int wrow = qt * 128 + wave * 32;         // wave's first Q row (32 rows)

    const f16* Qb  = Q  + ((size_t)(b * NHs  + h)  * Ssz) * HDs;
    const f16* Kg  = Kq + ((size_t)(b * NKVs + kh) * Ssz) * HDs;
    const f16* Vtg = Vt + ((size_t)(b * NKVs + kh) * HDs) * Ssz;

    __shared__ __align__(16) f16 Ks[32 * 256];   // [kv][d], chunks ^ (row&7)
    __shared__ __align__(16) f16 Vs[256 * 32];   // [d][kv], chunks ^ ((row>>1)&3)
    __shared__ __align__(16) f16 Pl[4 * 32 * 40];
    f16* Pw = Pl + wave * 32 * 40;

    const int k_r  = lane >> 5;          // row within staged pair
    const int k_c  = lane & 31;          // 16B chunk within 512B row
    const int v_r  = lane >> 2;          // d-row within 16-group
    const int v_gc = (lane & 3) ^ ((v_r >> 1) & 3);  // pre-swizzled global kv-chunk

    f16x8 qf0[8], qf1[8];
    {
        const f16* qrow0 = Qb + (size_t)(wrow + l15) * HDs + quad * 8;
        const f16* qrow1 = qrow0 + (size_t)16 * HDs;
#pragma unroll
        for (int ks = 0; ks < 8; ks++) {
            qf0[ks] = *(const f16x8*)(qrow0 + ks * 32);
            qf1[ks] = *(const f16x8*)(qrow1 + ks * 32);
        }
    }

    const f32x4 fz = {0.f, 0.f, 0.f, 0.f};
    f32x4 accO0[16], accO1[16];
#pragma unroll
    for (int jn = 0; jn < 16; jn++) { accO0[jn] = fz; accO1[jn] = fz; }
    float mrow0[4], mrow1[4], lp0[4], lp1[4];
#pragma unroll
    for (int r = 0; r < 4; r++) { mrow0[r] = -1e30f; mrow1[r] = -1e30f; lp0[r] = 0.f; lp1[r] = 0.f; }

    const int nk = 4 * qt + 4;
    const int wave_max_row = wrow + 31;
    const int kswz = l15 & 7;             // K read swizzle (rows l15 and 16+l15 share &7)
    const int vswz = (l15 >> 1) & 3;      // V read swizzle

    for (int kt = 0; kt < nk; kt++) {
        const int kvb = kt * 32;
        __syncthreads();   // previous tile fully consumed
#pragma unroll
        for (int t = 0; t < 4; t++) {
            const int r2 = wave * 8 + t * 2;
            const int gc = k_c ^ ((2 * t + k_r) & 7);   // (row&7) since wave*8 ≡ 0 (mod 8)
            async16(Kg + (size_t)(kvb + r2 + k_r) * 256 + gc * 8, Ks + r2 * 256);
        }
#pragma unroll
        for (int t = 0; t < 4; t++) {
            const int d0 = wave * 64 + t * 16;
            async16(Vtg + (size_t)(d0 + v_r) * Ssz + kvb + v_gc * 8, Vs + d0 * 32);
        }
        __syncthreads();   // drains vmcnt(0): tile visible

        if (kvb <= wave_max_row) {
            f32x4 s00 = fz, s01 = fz, s10 = fz, s11 = fz;
#pragma unroll
            for (int ks = 0; ks < 8; ks++) {
                const int cpos = ((ks * 4 + quad) ^ kswz) * 8;
                f16x8 kf0 = *(const f16x8*)(Ks + l15 * 256 + cpos);
                f16x8 kf1 = *(const f16x8*)(Ks + (16 + l15) * 256 + cpos);
                s00 = __builtin_amdgcn_mfma_f32_16x16x32_f16(qf0[ks], kf0, s00, 0, 0, 0);
                s01 = __builtin_amdgcn_mfma_f32_16x16x32_f16(qf0[ks], kf1, s01, 0, 0, 0);
                s10 = __builtin_amdgcn_mfma_f32_16x16x32_f16(qf1[ks], kf0, s10, 0, 0, 0);
                s11 = __builtin_amdgcn_mfma_f32_16x16x32_f16(qf1[ks], kf1, s11, 0, 0, 0);
            }
            float a0[4], a1[4];
            bool need = false;
            const bool diag = (kvb + 31 > wrow);   // any masking in this tile
#pragma unroll
            for (int r = 0; r < 4; r++) {
                // subtile 0: rows wrow + quad*4 + r
                float x0 = s00[r], x1 = s01[r];
                const int row0 = wrow + quad * 4 + r;
                if (diag) {
                    if (kvb + l15 > row0)      x0 = -1e30f;
                    if (kvb + 16 + l15 > row0) x1 = -1e30f;
                }
                float rmax = row_max16(fmaxf(x0, x1));
                float mold = mrow0[r];
                bool upd = rmax > mold + 8.f;      // defer-max, THR=8
                float mnew = upd ? rmax : mold;
                a0[r] = upd ? __expf(mold - rmax) : 1.0f;
                need = need || upd;
                float p0 = __expf(x0 - mnew);
                float p1 = __expf(x1 - mnew);
                lp0[r] = lp0[r] * a0[r] + (p0 + p1);
                mrow0[r] = mnew;
                Pw[(quad * 4 + r) * 40 + l15]      = (f16)p0;
                Pw[(quad * 4 + r) * 40 + 16 + l15] = (f16)p1;
                // subtile 1: rows wrow + 16 + quad*4 + r
                float y0 = s10[r], y1 = s11[r];
                const int row1 = row0 + 16;
                if (diag) {
                    if (kvb + l15 > row1)      y0 = -1e30f;
                    if (kvb + 16 + l15 > row1) y1 = -1e30f;
                }
                float rmax1 = row_max16(fmaxf(y0, y1));
                float mold1 = mrow1[r];
                bool upd1 = rmax1 > mold1 + 8.f;
                float mnew1 = upd1 ? rmax1 : mold1;
                a1[r] = upd1 ? __expf(mold1 - rmax1) : 1.0f;
                need = need || upd1;
                float q0 = __expf(y0 - mnew1);
                float q1 = __expf(y1 - mnew1);
                lp1[r] = lp1[r] * a1[r] + (q0 + q1);
                mrow1[r] = mnew1;
                Pw[(16 + quad * 4 + r) * 40 + l15]      = (f16)q0;
                Pw[(16 + quad * 4 + r) * 40 + 16 + l15] = (f16)q1;
            }
            if (__any(need)) {
#pragma unroll
                for (int jn = 0; jn < 16; jn++) {
                    f32x4 t0 = accO0[jn], t1 = accO1[jn];
                    t0[0] *= a0[0]; t0[1] *= a0[1]; t0[2] *= a0[2]; t0[3] *= a0[3];
                    t1[0] *= a1[0]; t1[1] *= a1[1]; t1[2] *= a1[2]; t1[3] *= a1[3];
                    accO0[jn] = t0; accO1[jn] = t1;
                }
            }
            // P (C-layout) -> A-layout via same-wave LDS round trip
            f16x8 pf0 = *(const f16x8*)(Pw + l15 * 40 + quad * 8);
            f16x8 pf1 = *(const f16x8*)(Pw + (16 + l15) * 40 + quad * 8);
#pragma unroll
            for (int jn = 0; jn < 16; jn++) {
                f16x8 vf = *(const f16x8*)(Vs + (jn * 16 + l15) * 32 + (quad ^ vswz) * 8);
                accO0[jn] = __builtin_amdgcn_mfma_f32_16x16x32_f16(pf0, vf, accO0[jn], 0, 0, 0);
                accO1[jn] = __builtin_amdgcn_mfma_f32_16x16x32_f16(pf1, vf, accO1[jn], 0, 0, 0);
            }
        }
    }
#pragma unroll
    for (int r = 0; r < 4; r++) {
        const int row0 = wrow + quad * 4 + r;
        const float inv0 = 1.0f / row_sum16(lp0[r]);
        f16* orow0 = O + ((size_t)(b * Ssz) + row0) * (NHs * HDs) + h * HDs;
#pragma unroll
        for (int jn = 0; jn < 16; jn++)
            orow0[jn * 16 + l15] = (f16)(accO0[jn][r] * inv0);
        const int row1 = row0 + 16;
        const float inv1 = 1.0f / row_sum16(lp1[r]);
        f16* orow1 = O + ((size_t)(b * Ssz) + row1) * (NHs * HDs) + h * HDs;
#pragma unroll
        for (int jn = 0; jn < 16; jn++)
            orow1[jn * 16 + l15] = (f16)(accO1[jn][r] * inv1);
    }
}

// ---------------- launcher ----------------
extern "C" void kernel_launch(void* const* d_in, const int* in_sizes, int n_in,
                              void* d_out, int out_size, void* d_ws, size_t ws_size,
                              hipStream_t stream) {
    const float* hs   = (const float*)d_in[0];
    const float* Wq   = (const float*)d_in[1];
    const float* Wk   = (const float*)d_in[2];
    const float* Wv   = (const float*)d_in[3];
    const float* Wo   = (const float*)d_in[4];
    const float* cosb = (const float*)d_in[5];
    const float* sinb = (const float*)d_in[6];
    float* out = (float*)d_out;

    char* ws = (char*)d_ws;
    f16*   hs_h = (f16*)(ws);                    // 25165824 B  (hidden f16)
    f16*   wo_h = (f16*)(ws + 25165824);         // 25165824 B  (Wo f16)
    float* proj = (float*)(ws + 50331648);       // 67108864 B  (reused)
    f16*   q_h  = (f16*)(ws + 117440512);        // 33554432 B  (Wq f16 first, then roped Q)
    f16*   k_h  = (f16*)(ws + 150994944);        // 16777216 B  (Wk f16 first, then quant K)
    f16*   vt_h = (f16*)(ws + 167772160);        // 16777216 B  (Wv f16 first, then Vt)
    f16*   ao_h = (f16*)proj;                    // attn output reuses proj region

    // one fused cast: hs->hs_h, Wq->q_h, Wk->k_h, Wv->vt_h, Wo->wo_h
    cast_all_kernel<<<N4_TOT / 256, 256, 0, stream>>>(
        (const float4*)hs, (const float4*)Wq, (const float4*)Wk,
        (const float4*)Wv, (const float4*)Wo,
        (f16x4*)hs_h, (f16x4*)q_h, (f16x4*)k_h, (f16x4*)vt_h, (f16x4*)wo_h);

    // Q projection (B = Wq living in q_h region; rope then overwrites q_h)
    gemm_nt_f16<<<dim3(4096 / 128, 4096 / 128), 256, 0, stream>>>(hs_h, q_h, proj, 4096, 4096, 3072);
    rope_q_kernel<<<dim3(Ssz, NHs, Bsz), 256, 0, stream>>>(proj, cosb, sinb, q_h);
    // K projection + quantize (B = Wk in k_h; then overwritten)
    gemm_nt_f16<<<dim3(2048 / 128, 4096 / 128), 256, 0, stream>>>(hs_h, k_h, proj, 4096, 2048, 3072);
    rope_quant_k_kernel<<<dim3(Ssz, NKVs, Bsz), 256, 0, stream>>>(proj, cosb, sinb, k_h);
    // V projection + transpose (B = Wv in vt_h; then overwritten)
    gemm_nt_f16<<<dim3(2048 / 128, 4096 / 128), 256, 0, stream>>>(hs_h, vt_h, proj, 4096, 2048, 3072);
    transpose_v_kernel<<<dim3(Ssz / 64, (NKVs * HDs) / 64, Bsz), 256, 0, stream>>>(proj, vt_h);
    // attention: Q-tile 128 -> 512 blocks, XCD-remapped inside kernel
    attn_kernel<<<dim3(Ssz / 128, NHs, Bsz), 256, 0, stream>>>(q_h, k_h, vt_h, ao_h);
    // output projection -> d_out
    gemm_nt_f16<<<dim3(3072 / 128, 4096 / 128), 256, 0, stream>>>(ao_h, wo_h, out, 4096, 3072, 4096);
}

// Round 4
// 934.350 us; speedup vs baseline: 1.2036x; 1.0389x over previous
//
#include <hip/hip_runtime.h>
#include <math.h>

#define Bsz 2
#define Ssz 2048
#define HIDs 3072
#define NHs 16
#define NKVs 8
#define HDs 256

typedef _Float16 f16;
typedef _Float16 f16x8 __attribute__((ext_vector_type(8)));
typedef _Float16 f16x4 __attribute__((ext_vector_type(4)));
typedef float f32x4 __attribute__((ext_vector_type(4)));

__device__ __forceinline__ void async16(const f16* g, f16* l) {
    __builtin_amdgcn_global_load_lds(
        (const __attribute__((address_space(1))) void*)g,
        (__attribute__((address_space(3))) void*)l, 16, 0, 0);
}

// 16-lane (quad-row) reductions on the VALU pipe via DPP row_ror.
__device__ __forceinline__ float row_max16(float v) {
    int t;
    t = __builtin_amdgcn_mov_dpp(__float_as_int(v), 0x121, 0xf, 0xf, false);
    v = fmaxf(v, __int_as_float(t));
    t = __builtin_amdgcn_mov_dpp(__float_as_int(v), 0x122, 0xf, 0xf, false);
    v = fmaxf(v, __int_as_float(t));
    t = __builtin_amdgcn_mov_dpp(__float_as_int(v), 0x124, 0xf, 0xf, false);
    v = fmaxf(v, __int_as_float(t));
    t = __builtin_amdgcn_mov_dpp(__float_as_int(v), 0x128, 0xf, 0xf, false);
    v = fmaxf(v, __int_as_float(t));
    return v;
}
__device__ __forceinline__ float row_sum16(float v) {
    int t;
    t = __builtin_amdgcn_mov_dpp(__float_as_int(v), 0x121, 0xf, 0xf, false);
    v = v + __int_as_float(t);
    t = __builtin_amdgcn_mov_dpp(__float_as_int(v), 0x122, 0xf, 0xf, false);
    v = v + __int_as_float(t);
    t = __builtin_amdgcn_mov_dpp(__float_as_int(v), 0x124, 0xf, 0xf, false);
    v = v + __int_as_float(t);
    t = __builtin_amdgcn_mov_dpp(__float_as_int(v), 0x128, 0xf, 0xf, false);
    v = v + __int_as_float(t);
    return v;
}

// ---------------- fused cast fp32 -> fp16 for all 5 inputs (1 launch) ----------------
#define N4_HS  3145728
#define N4_WQ  3145728
#define N4_WK  1572864
#define N4_WV  1572864
#define N4_WO  3145728
#define N4_TOT (N4_HS + N4_WQ + N4_WK + N4_WV + N4_WO)

__global__ void cast_all_kernel(const float4* __restrict__ hs, const float4* __restrict__ wq,
                                const float4* __restrict__ wk, const float4* __restrict__ wv,
                                const float4* __restrict__ wo,
                                f16x4* __restrict__ hs_h, f16x4* __restrict__ wq_h,
                                f16x4* __restrict__ wk_h, f16x4* __restrict__ wv_h,
                                f16x4* __restrict__ wo_h) {
    int i = blockIdx.x * blockDim.x + threadIdx.x;
    const float4* src; f16x4* dst; int off;
    if (i < N4_HS)                       { src = hs; dst = hs_h; off = i; }
    else if (i < N4_HS + N4_WQ)          { src = wq; dst = wq_h; off = i - N4_HS; }
    else if (i < N4_HS + N4_WQ + N4_WK)  { src = wk; dst = wk_h; off = i - (N4_HS + N4_WQ); }
    else if (i < N4_TOT - N4_WO)         { src = wv; dst = wv_h; off = i - (N4_HS + N4_WQ + N4_WK); }
    else                                 { src = wo; dst = wo_h; off = i - (N4_TOT - N4_WO); }
    float4 v = src[off];
    f16x4 r;
    r[0] = (f16)v.x; r[1] = (f16)v.y; r[2] = (f16)v.z; r[3] = (f16)v.w;
    dst[off] = r;
}

// ---- NT GEMM (m97 structure): C[M,N] = A[M,K]*B[N,K]^T, f16 in, f32 out ----
__global__ __launch_bounds__(256) void gemm_nt_f16(
    const f16* __restrict__ A, const f16* __restrict__ Bm, float* __restrict__ C,
    int M, int N, int K)
{
    __shared__ __align__(16) f16 As[128 * 32];
    __shared__ __align__(16) f16 Bs[128 * 32];
    const int tid  = threadIdx.x;
    const int wave = tid >> 6, lane = tid & 63;
    const int l15  = lane & 15, quad = lane >> 4;
    const int m0 = blockIdx.y * 128, n0 = blockIdx.x * 128;
    const int wm = (wave >> 1) * 64, wn = (wave & 1) * 64;
    const int srow = wave * 32 + (lane >> 2);
    const int scol = (lane & 3) * 8;

    f32x4 acc[4][4];
    const f32x4 fz = {0.f, 0.f, 0.f, 0.f};
#pragma unroll
    for (int i = 0; i < 4; i++)
#pragma unroll
        for (int j = 0; j < 4; j++) acc[i][j] = fz;

    const f16* Ag0 = A  + (size_t)(m0 + srow) * K + scol;
    const f16* Ag1 = A  + (size_t)(m0 + srow + 16) * K + scol;
    const f16* Bg0 = Bm + (size_t)(n0 + srow) * K + scol;
    const f16* Bg1 = Bm + (size_t)(n0 + srow + 16) * K + scol;
    f16* Al0 = As + (wave * 32) * 32;
    f16* Al1 = As + (wave * 32 + 16) * 32;
    f16* Bl0 = Bs + (wave * 32) * 32;
    f16* Bl1 = Bs + (wave * 32 + 16) * 32;

    for (int k0 = 0; k0 < K; k0 += 32) {
        __syncthreads();
        async16(Ag0 + k0, Al0);
        async16(Ag1 + k0, Al1);
        async16(Bg0 + k0, Bl0);
        async16(Bg1 + k0, Bl1);
        __syncthreads();
        f16x8 af[4], bfr[4];
#pragma unroll
        for (int i = 0; i < 4; i++)
            af[i] = *(const f16x8*)(As + (wm + i * 16 + l15) * 32 + quad * 8);
#pragma unroll
        for (int j = 0; j < 4; j++)
            bfr[j] = *(const f16x8*)(Bs + (wn + j * 16 + l15) * 32 + quad * 8);
#pragma unroll
        for (int i = 0; i < 4; i++)
#pragma unroll
            for (int j = 0; j < 4; j++)
                acc[i][j] = __builtin_amdgcn_mfma_f32_16x16x32_f16(af[i], bfr[j], acc[i][j], 0, 0, 0);
    }
#pragma unroll
    for (int i = 0; i < 4; i++) {
        const int r = m0 + wm + i * 16 + quad * 4;
#pragma unroll
        for (int j = 0; j < 4; j++) {
            const int c = n0 + wn + j * 16 + l15;
#pragma unroll
            for (int rr = 0; rr < 4; rr++)
                C[(size_t)(r + rr) * N + c] = acc[i][j][rr];
        }
    }
}

// ---------------- RoPE for Q (scale 1/sqrt(HD) folded in) ----------------
__global__ void rope_q_kernel(const float* __restrict__ qp, const float* __restrict__ cosb,
                              const float* __restrict__ sinb, f16* __restrict__ qo) {
    const int s = blockIdx.x, h = blockIdx.y, b = blockIdx.z;
    const int d = threadIdx.x;
    const float* row = qp + (size_t)(b * Ssz + s) * (NHs * HDs) + h * HDs;
    float x = row[d];
    float other = (d < 128) ? -row[d + 128] : row[d - 128];
    float val = (x * cosb[s * HDs + d] + other * sinb[s * HDs + d]) * 0.0625f;
    qo[((size_t)(b * NHs + h) * Ssz + s) * HDs + d] = (f16)val;
}

// ---------------- RoPE + BFP4 quantize for K ----------------
__global__ void rope_quant_k_kernel(const float* __restrict__ kp, const float* __restrict__ cosb,
                                    const float* __restrict__ sinb, f16* __restrict__ ko) {
    const int s = blockIdx.x, h = blockIdx.y, b = blockIdx.z;
    const int d = threadIdx.x;
    const float* row = kp + (size_t)(b * Ssz + s) * (NKVs * HDs) + h * HDs;
    float x = row[d];
    float other = (d < 128) ? -row[d + 128] : row[d - 128];
    float val = x * cosb[s * HDs + d] + other * sinb[s * HDs + d];
    __shared__ float red[256];
    red[d] = fabsf(val);
    __syncthreads();
    for (int off = 64; off >= 1; off >>= 1) {
        if ((d & 127) < off) red[d] = fmaxf(red[d], red[d + off]);
        __syncthreads();
    }
    float maxabs = red[d & 128];
    float out;
    if (maxabs > 0.f) {
        int ex;
        frexpf(maxabs, &ex);                 // floor(log2(maxabs)) = ex-1 exactly
        float scale = ldexpf(1.0f, ex - 3);  // 2^(e - (bits-2)), bits=4
        float q = rintf(val / scale);
        q = fminf(7.f, fmaxf(-7.f, q));
        out = q * scale;
    } else out = 0.f;
    ko[((size_t)(b * NKVs + h) * Ssz + s) * HDs + d] = (f16)out;
}

// -------- V: fp32 proj [b][s][kh*256+d] -> f16 Vt [b][kh][d][s] (transposed) --------
__global__ __launch_bounds__(256) void transpose_v_kernel(
    const float* __restrict__ proj, f16* __restrict__ vt)
{
    const int s0 = blockIdx.x * 64, c0 = blockIdx.y * 64, b = blockIdx.z;
    const int tid = threadIdx.x;
    __shared__ f16 T[64 * 72];
    {
        const int r = tid >> 2, cc = (tid & 3) * 16;
        const float* src = proj + (size_t)(b * Ssz + s0 + r) * (NKVs * HDs) + c0 + cc;
        f16 tmp[16];
#pragma unroll
        for (int q4 = 0; q4 < 4; q4++) {
            float4 v = *(const float4*)(src + q4 * 4);
            tmp[q4 * 4 + 0] = (f16)v.x; tmp[q4 * 4 + 1] = (f16)v.y;
            tmp[q4 * 4 + 2] = (f16)v.z; tmp[q4 * 4 + 3] = (f16)v.w;
        }
        *(f16x8*)(T + r * 72 + cc)     = *(f16x8*)(tmp);
        *(f16x8*)(T + r * 72 + cc + 8) = *(f16x8*)(tmp + 8);
    }
    __syncthreads();
    {
        const int d = tid >> 2, sc = (tid & 3) * 16;
        f16 tmp[16];
#pragma unroll
        for (int j = 0; j < 16; j++) tmp[j] = T[(sc + j) * 72 + d];
        const int col = c0 + d;
        const int kh = col >> 8, dd = col & 255;
        f16* dst = vt + ((size_t)(b * NKVs + kh) * HDs + dd) * Ssz + s0 + sc;
        *(f16x8*)(dst)     = *(f16x8*)(tmp);
        *(f16x8*)(dst + 8) = *(f16x8*)(tmp + 8);
    }
}

// ---- flash attention v9: causal-BALANCED 8-wave blocks + XCD locality.
// Each 512-thread block owns TWO 128-row Q chunks of one head: c_short=qtp
// (waves 0-3) and c_long=15-qtp (waves 4-7). Every block = exactly 68
// tile-computes -> no tail imbalance; grid 256 = 1 block/CU, all CUs busy
// to the end. KV staged once per tile by all 8 waves (4 async16/lane).
// v6 swizzles (K: chunk^(row&7), V: chunk^((row>>1)&3)), defer-max, and
// R3's verified XCD remap (each (b,kh) K/V set pinned to one XCD) kept.
__global__ __launch_bounds__(512, 1) void attn_kernel(
    const f16* __restrict__ Q,   // [B][NH][S][HD], pre-scaled by 1/16
    const f16* __restrict__ Kq,  // [B][NKV][S][HD] quantized
    const f16* __restrict__ Vt,  // [B][NKV][HD][S] transposed
    f16* __restrict__ O)         // [B][S][NH*HD]
{
    // ---- XCD-locality remap (bijective over 256 blocks) ----
    // 16 (b,kh) pairs -> 2 per XCD; 16 blocks per pair (2 h * 8 qtp).
    const int flat = blockIdx.x;
    const int xcd  = flat & 7;
    const int slot = flat >> 3;          // 0..31
    const int psel = slot >> 4;          // 0|1: which of this XCD's 2 pairs
    const int pair = (xcd << 1) | psel;  // 0..15 == (b*8 + kh)
    const int b    = pair >> 3;
    const int kh   = pair & 7;
    const int sub  = slot & 15;          // 0..15 within pair
    const int h    = (kh << 1) | (sub >> 3);
    const int qtp  = sub & 7;            // chunk-pair index 0..7
    const int c_short = qtp;             // 128-row chunk indices
    const int c_long  = 15 - qtp;

    const int tid = threadIdx.x;
    const int wave = tid >> 6, lane = tid & 63;
    const int l15 = lane & 15, quad = lane >> 4;
    // waves 0-3 -> chunk c_short, waves 4-7 -> chunk c_long; 32 rows/wave
    const int wrow = (wave < 4) ? (c_short * 128 + wave * 32)
                                : (c_long * 128 + (wave - 4) * 32);

    const f16* Qb  = Q  + ((size_t)(b * NHs  + h)  * Ssz) * HDs;
    const f16* Kg  = Kq + ((size_t)(b * NKVs + kh) * Ssz) * HDs;
    const f16* Vtg = Vt + ((size_t)(b * NKVs + kh) * HDs) * Ssz;

    __shared__ __align__(16) f16 Ks[32 * 256];   // [kv][d], chunks ^ (row&7)
    __shared__ __align__(16) f16 Vs[256 * 32];   // [d][kv], chunks ^ ((row>>1)&3)
    __shared__ __align__(16) f16 Pl[8 * 32 * 40];
    f16* Pw = Pl + wave * 32 * 40;

    const int k_r  = lane >> 5;          // row within staged pair
    const int k_c  = lane & 31;          // 16B chunk within 512B row
    const int v_r  = lane >> 2;          // d-row within 16-group
    const int v_gc = (lane & 3) ^ ((v_r >> 1) & 3);  // pre-swizzled global kv-chunk

    f16x8 qf0[8], qf1[8];
    {
        const f16* qrow0 = Qb + (size_t)(wrow + l15) * HDs + quad * 8;
        const f16* qrow1 = qrow0 + (size_t)16 * HDs;
#pragma unroll
        for (int ks = 0; ks < 8; ks++) {
            qf0[ks] = *(const f16x8*)(qrow0 + ks * 32);
            qf1[ks] = *(const f16x8*)(qrow1 + ks * 32);
        }
    }

    const f32x4 fz = {0.f, 0.f, 0.f, 0.f};
    f32x4 accO0[16], accO1[16];
#pragma unroll
    for (int jn = 0; jn < 16; jn++) { accO0[jn] = fz; accO1[jn] = fz; }
    float mrow0[4], mrow1[4], lp0[4], lp1[4];
#pragma unroll
    for (int r = 0; r < 4; r++) { mrow0[r] = -1e30f; mrow1[r] = -1e30f; lp0[r] = 0.f; lp1[r] = 0.f; }

    const int nk = 4 * c_long + 4;       // KV tiles for the longer chunk
    const int wave_max_row = wrow + 31;
    const int kswz = l15 & 7;             // K read swizzle (rows l15 and 16+l15 share &7)
    const int vswz = (l15 >> 1) & 3;      // V read swizzle

    for (int kt = 0; kt < nk; kt++) {
        const int kvb = kt * 32;
        __syncthreads();   // previous tile fully consumed
        // ---- shared staging: 8 waves, 4 async16/lane ----
#pragma unroll
        for (int t = 0; t < 2; t++) {
            const int r2 = wave * 4 + t * 2;                // K rows r2, r2+1
            const int gc = k_c ^ ((r2 + k_r) & 7);          // row&7 swizzle
            async16(Kg + (size_t)(kvb + r2 + k_r) * 256 + gc * 8, Ks + r2 * 256);
        }
#pragma unroll
        for (int t = 0; t < 2; t++) {
            const int d0 = wave * 32 + t * 16;              // V d-rows d0..d0+15
            async16(Vtg + (size_t)(d0 + v_r) * Ssz + kvb + v_gc * 8, Vs + d0 * 32);
        }
        __syncthreads();   // drains vmcnt(0): tile visible

        if (kvb <= wave_max_row) {
            f32x4 s00 = fz, s01 = fz, s10 = fz, s11 = fz;
#pragma unroll
            for (int ks = 0; ks < 8; ks++) {
                const int cpos = ((ks * 4 + quad) ^ kswz) * 8;
                f16x8 kf0 = *(const f16x8*)(Ks + l15 * 256 + cpos);
                f16x8 kf1 = *(const f16x8*)(Ks + (16 + l15) * 256 + cpos);
                s00 = __builtin_amdgcn_mfma_f32_16x16x32_f16(qf0[ks], kf0, s00, 0, 0, 0);
                s01 = __builtin_amdgcn_mfma_f32_16x16x32_f16(qf0[ks], kf1, s01, 0, 0, 0);
                s10 = __builtin_amdgcn_mfma_f32_16x16x32_f16(qf1[ks], kf0, s10, 0, 0, 0);
                s11 = __builtin_amdgcn_mfma_f32_16x16x32_f16(qf1[ks], kf1, s11, 0, 0, 0);
            }
            float a0[4], a1[4];
            bool need = false;
            const bool diag = (kvb + 31 > wrow);   // any masking in this tile
#pragma unroll
            for (int r = 0; r < 4; r++) {
                // subtile 0: rows wrow + quad*4 + r
                float x0 = s00[r], x1 = s01[r];
                const int row0 = wrow + quad * 4 + r;
                if (diag) {
                    if (kvb + l15 > row0)      x0 = -1e30f;
                    if (kvb + 16 + l15 > row0) x1 = -1e30f;
                }
                float rmax = row_max16(fmaxf(x0, x1));
                float mold = mrow0[r];
                bool upd = rmax > mold + 8.f;      // defer-max, THR=8
                float mnew = upd ? rmax : mold;
                a0[r] = upd ? __expf(mold - rmax) : 1.0f;
                need = need || upd;
                float p0 = __expf(x0 - mnew);
                float p1 = __expf(x1 - mnew);
                lp0[r] = lp0[r] * a0[r] + (p0 + p1);
                mrow0[r] = mnew;
                Pw[(quad * 4 + r) * 40 + l15]      = (f16)p0;
                Pw[(quad * 4 + r) * 40 + 16 + l15] = (f16)p1;
                // subtile 1: rows wrow + 16 + quad*4 + r
                float y0 = s10[r], y1 = s11[r];
                const int row1 = row0 + 16;
                if (diag) {
                    if (kvb + l15 > row1)      y0 = -1e30f;
                    if (kvb + 16 + l15 > row1) y1 = -1e30f;
                }
                float rmax1 = row_max16(fmaxf(y0, y1));
                float mold1 = mrow1[r];
                bool upd1 = rmax1 > mold1 + 8.f;
                float mnew1 = upd1 ? rmax1 : mold1;
                a1[r] = upd1 ? __expf(mold1 - rmax1) : 1.0f;
                need = need || upd1;
                float q0 = __expf(y0 - mnew1);
                float q1 = __expf(y1 - mnew1);
                lp1[r] = lp1[r] * a1[r] + (q0 + q1);
                mrow1[r] = mnew1;
                Pw[(16 + quad * 4 + r) * 40 + l15]      = (f16)q0;
                Pw[(16 + quad * 4 + r) * 40 + 16 + l15] = (f16)q1;
            }
            if (__any(need)) {
#pragma unroll
                for (int jn = 0; jn < 16; jn++) {
                    f32x4 t0 = accO0[jn], t1 = accO1[jn];
                    t0[0] *= a0[0]; t0[1] *= a0[1]; t0[2] *= a0[2]; t0[3] *= a0[3];
                    t1[0] *= a1[0]; t1[1] *= a1[1]; t1[2] *= a1[2]; t1[3] *= a1[3];
                    accO0[jn] = t0; accO1[jn] = t1;
                }
            }
            // P (C-layout) -> A-layout via same-wave LDS round trip
            f16x8 pf0 = *(const f16x8*)(Pw + l15 * 40 + quad * 8);
            f16x8 pf1 = *(const f16x8*)(Pw + (16 + l15) * 40 + quad * 8);
#pragma unroll
            for (int jn = 0; jn < 16; jn++) {
                f16x8 vf = *(const f16x8*)(Vs + (jn * 16 + l15) * 32 + (quad ^ vswz) * 8);
                accO0[jn] = __builtin_amdgcn_mfma_f32_16x16x32_f16(pf0, vf, accO0[jn], 0, 0, 0);
                accO1[jn] = __builtin_amdgcn_mfma_f32_16x16x32_f16(pf1, vf, accO1[jn], 0, 0, 0);
            }
        }
    }
#pragma unroll
    for (int r = 0; r < 4; r++) {
        const int row0 = wrow + quad * 4 + r;
        const float inv0 = 1.0f / row_sum16(lp0[r]);
        f16* orow0 = O + ((size_t)(b * Ssz) + row0) * (NHs * HDs) + h * HDs;
#pragma unroll
        for (int jn = 0; jn < 16; jn++)
            orow0[jn * 16 + l15] = (f16)(accO0[jn][r] * inv0);
        const int row1 = row0 + 16;
        const float inv1 = 1.0f / row_sum16(lp1[r]);
        f16* orow1 = O + ((size_t)(b * Ssz) + row1) * (NHs * HDs) + h * HDs;
#pragma unroll
        for (int jn = 0; jn < 16; jn++)
            orow1[jn * 16 + l15] = (f16)(accO1[jn][r] * inv1);
    }
}

// ---------------- launcher ----------------
extern "C" void kernel_launch(void* const* d_in, const int* in_sizes, int n_in,
                              void* d_out, int out_size, void* d_ws, size_t ws_size,
                              hipStream_t stream) {
    const float* hs   = (const float*)d_in[0];
    const float* Wq   = (const float*)d_in[1];
    const float* Wk   = (const float*)d_in[2];
    const float* Wv   = (const float*)d_in[3];
    const float* Wo   = (const float*)d_in[4];
    const float* cosb = (const float*)d_in[5];
    const float* sinb = (const float*)d_in[6];
    float* out = (float*)d_out;

    char* ws = (char*)d_ws;
    f16*   hs_h = (f16*)(ws);                    // 25165824 B  (hidden f16)
    f16*   wo_h = (f16*)(ws + 25165824);         // 25165824 B  (Wo f16)
    float* proj = (float*)(ws + 50331648);       // 67108864 B  (reused)
    f16*   q_h  = (f16*)(ws + 117440512);        // 33554432 B  (Wq f16 first, then roped Q)
    f16*   k_h  = (f16*)(ws + 150994944);        // 16777216 B  (Wk f16 first, then quant K)
    f16*   vt_h = (f16*)(ws + 167772160);        // 16777216 B  (Wv f16 first, then Vt)
    f16*   ao_h = (f16*)proj;                    // attn output reuses proj region

    // one fused cast: hs->hs_h, Wq->q_h, Wk->k_h, Wv->vt_h, Wo->wo_h
    cast_all_kernel<<<N4_TOT / 256, 256, 0, stream>>>(
        (const float4*)hs, (const float4*)Wq, (const float4*)Wk,
        (const float4*)Wv, (const float4*)Wo,
        (f16x4*)hs_h, (f16x4*)q_h, (f16x4*)k_h, (f16x4*)vt_h, (f16x4*)wo_h);

    // Q projection (B = Wq living in q_h region; rope then overwrites q_h)
    gemm_nt_f16<<<dim3(4096 / 128, 4096 / 128), 256, 0, stream>>>(hs_h, q_h, proj, 4096, 4096, 3072);
    rope_q_kernel<<<dim3(Ssz, NHs, Bsz), 256, 0, stream>>>(proj, cosb, sinb, q_h);
    // K projection + quantize (B = Wk in k_h; then overwritten)
    gemm_nt_f16<<<dim3(2048 / 128, 4096 / 128), 256, 0, stream>>>(hs_h, k_h, proj, 4096, 2048, 3072);
    rope_quant_k_kernel<<<dim3(Ssz, NKVs, Bsz), 256, 0, stream>>>(proj, cosb, sinb, k_h);
    // V projection + transpose (B = Wv in vt_h; then overwritten)
    gemm_nt_f16<<<dim3(2048 / 128, 4096 / 128), 256, 0, stream>>>(hs_h, vt_h, proj, 4096, 2048, 3072);
    transpose_v_kernel<<<dim3(Ssz / 64, (NKVs * HDs) / 64, Bsz), 256, 0, stream>>>(proj, vt_h);
    // attention: 256 balanced blocks (8 qt-pairs x 16 h x 2 b), 512 thr
    attn_kernel<<<dim3(256, 1, 1), 512, 0, stream>>>(q_h, k_h, vt_h, ao_h);
    // output projection -> d_out
    gemm_nt_f16<<<dim3(3072 / 128, 4096 / 128), 256, 0, stream>>>(ao_h, wo_h, out, 4096, 3072, 4096);
}